// Round 4
// baseline (488.869 us; speedup 1.0000x reference)
//
#include <hip/hip_runtime.h>
#include <hip/hip_bf16.h>

#define NB 16
#define NC 256
#define NS 4096
#define NL 256
#define NE 256
#define NHH 4
#define HDD 64

using bf16 = __hip_bfloat16;
typedef short bf16x8 __attribute__((ext_vector_type(8)));
typedef float f32x4 __attribute__((ext_vector_type(4)));

struct U16 { uint a, b, c, d; };

__device__ __forceinline__ float bf16r(float x) {
    return __bfloat162float(__float2bfloat16(x));
}
__device__ __forceinline__ float rsqrt_nr(float x) {
    float r = rsqrtf(x);
    r = r * (1.5f - 0.5f * x * r * r);
    return r;
}
__device__ __forceinline__ float wave_sum(float v) {
#pragma unroll
    for (int o = 32; o > 0; o >>= 1) v += __shfl_down(v, o, 64);
    return v;
}
__device__ __forceinline__ ushort us(float x) {
    bf16 h = __float2bfloat16(x);
    return *(ushort*)&h;
}
__device__ __forceinline__ uint pack2(float a, float b) {
    return (uint)us(a) | ((uint)us(b) << 16);
}

// ---------------- K0: transpose weights to bf16 [out][in]
__global__ void __launch_bounds__(256) wt_kernel(const float* __restrict__ Wq,
                                                 const float* __restrict__ Wk,
                                                 const float* __restrict__ Wv,
                                                 const float* __restrict__ Wo,
                                                 ushort* __restrict__ wqt,
                                                 ushort* __restrict__ wkt,
                                                 ushort* __restrict__ wvt,
                                                 ushort* __restrict__ wot) {
    int m = blockIdx.x >> 3, strip = blockIdx.x & 7;
    const float* W = (m == 0) ? Wq : (m == 1) ? Wk : (m == 2) ? Wv : Wo;
    ushort* Wt = (m == 0) ? wqt : (m == 1) ? wkt : (m == 2) ? wvt : wot;
    int t = threadIdx.x;
    __shared__ float tile[32 * 257];
    int in0 = strip * 32;
    for (int i = 0; i < 32; i++) tile[i * 257 + t] = W[(size_t)(in0 + i) * 256 + t];
    __syncthreads();
    ushort vals[32];
#pragma unroll
    for (int i = 0; i < 32; i++) vals[i] = us(tile[i * 257 + t]);
#pragma unroll
    for (int i = 0; i < 32; i += 8)
        *(uint4*)(Wt + (size_t)t * 256 + in0 + i) = *(const uint4*)(vals + i);
}

// ---------------- K1: AdaLN modulation
__global__ void __launch_bounds__(256) mod_kernel(const float* __restrict__ ref_embeds,
                                                  const float* __restrict__ W_ada,
                                                  const float* __restrict__ b_ada,
                                                  float* __restrict__ mod) {
    int b = blockIdx.x, t = threadIdx.x;
    __shared__ float silu[NC];
    float x = ref_embeds[b * NC + t];
    silu[t] = x / (1.f + expf(-x));
    __syncthreads();
    for (int rep = 0; rep < 3; rep++) {
        int j = rep * NC + t;
        float acc = b_ada[j];
        for (int c = 0; c < NC; c++) acc += silu[c] * W_ada[c * 3 * NC + j];
        mod[b * 3 * NC + j] = acc;
    }
}

// ---------------- K2: LN(refs) -> K,V projections via MFMA
__global__ void __launch_bounds__(256) kv_kernel(const float* __restrict__ refs,
                                                 const float* __restrict__ lw,
                                                 const float* __restrict__ lb,
                                                 const ushort* __restrict__ Wkt,
                                                 const float* __restrict__ bk,
                                                 const ushort* __restrict__ Wvt,
                                                 const float* __restrict__ bv,
                                                 bf16* __restrict__ kbuf,
                                                 bf16* __restrict__ vbuf) {
    int blk = blockIdx.x;
    int b = blk >> 2;
    int l0 = (blk & 3) << 6;
    int t = threadIdx.x;
    __shared__ ushort At[64 * 264];
    __shared__ float lws[NC], lbs[NC];
    lws[t] = lw[t];
    lbs[t] = lb[t];
    int r = t >> 2, j = t & 3;
    const float* rp = refs + ((size_t)(b * NL + l0 + r)) * NC + j * 64;
    float v[64];
#pragma unroll
    for (int i = 0; i < 16; i++) {
        float4 f = *(const float4*)(rp + i * 4);
        v[i * 4 + 0] = f.x; v[i * 4 + 1] = f.y; v[i * 4 + 2] = f.z; v[i * 4 + 3] = f.w;
    }
    float s = 0;
#pragma unroll
    for (int i = 0; i < 64; i++) s += v[i];
    s += __shfl_xor(s, 1, 64);
    s += __shfl_xor(s, 2, 64);
    float mu = s * (1.f / NC);
    float vr = 0;
#pragma unroll
    for (int i = 0; i < 64; i++) {
        float d = v[i] - mu;
        vr += d * d;
    }
    vr += __shfl_xor(vr, 1, 64);
    vr += __shfl_xor(vr, 2, 64);
    float rs = rsqrt_nr(vr * (1.f / NC) + 1e-5f);
    __syncthreads();
    ushort nv[64];
#pragma unroll
    for (int i = 0; i < 64; i++) {
        int c = j * 64 + i;
        nv[i] = us((v[i] - mu) * rs * lws[c] + lbs[c]);
    }
#pragma unroll
    for (int i = 0; i < 64; i += 4)
        *(uint2*)(At + r * 264 + j * 64 + i) = *(const uint2*)(nv + i);
    __syncthreads();

    int w = t >> 6, lane = t & 63, l16 = lane & 15, quad = lane >> 4;
    int r0 = w * 16;
    f32x4 zero = {0.f, 0.f, 0.f, 0.f};
    f32x4 ak[16], av[16];
#pragma unroll
    for (int et = 0; et < 16; et++) { ak[et] = zero; av[et] = zero; }
    const ushort* ap = At + (r0 + l16) * 264 + quad * 8;
    const ushort* kp = Wkt + (size_t)l16 * NC + quad * 8;
    const ushort* vp = Wvt + (size_t)l16 * NC + quad * 8;
#pragma unroll
    for (int kc = 0; kc < 8; kc++) {
        bf16x8 a = *(const bf16x8*)(ap + kc * 32);
#pragma unroll
        for (int et = 0; et < 16; et++) {
            bf16x8 bbk = *(const bf16x8*)(kp + (size_t)et * 16 * NC + kc * 32);
            ak[et] = __builtin_amdgcn_mfma_f32_16x16x32_bf16(a, bbk, ak[et], 0, 0, 0);
        }
#pragma unroll
        for (int et = 0; et < 16; et++) {
            bf16x8 bbv = *(const bf16x8*)(vp + (size_t)et * 16 * NC + kc * 32);
            av[et] = __builtin_amdgcn_mfma_f32_16x16x32_bf16(a, bbv, av[et], 0, 0, 0);
        }
    }
#pragma unroll
    for (int et = 0; et < 16; et++) {
        int e = et * 16 + l16;
        float bkv = bk[e], bvv = bv[e];
#pragma unroll
        for (int rr = 0; rr < 4; rr++) {
            size_t row = (size_t)(b * NL + l0 + r0 + quad * 4 + rr);
            kbuf[row * NE + e] = __float2bfloat16(ak[et][rr] + bkv);
            vbuf[row * NE + e] = __float2bfloat16(av[et][rr] + bvv);
        }
    }
}

// ---------------- K2b: transpose V per head with PV-slot key permutation:
// vtbuf[bh][d][p] where p = m*32+quad*8+j holds V^T[d][key = m*32+quad*4+(j>>2)*16+(j&3)]
__global__ void __launch_bounds__(256) vt_kernel(const bf16* __restrict__ vbuf,
                                                 ushort* __restrict__ vtbuf) {
    int bh = blockIdx.x;
    int b = bh >> 2, h = bh & 3;
    int t = threadIdx.x;
    __shared__ ushort tile[64 * 264];  // [d][l]
    const ushort* vp = (const ushort*)vbuf + ((size_t)b * NL) * NE + h * HDD;
#pragma unroll
    for (int i = 0; i < 8; i++) {
        int l = i * 32 + (t >> 3);
        uint4 v = *(const uint4*)(vp + (size_t)l * NE + (t & 7) * 8);
        const ushort* v8 = (const ushort*)&v;
#pragma unroll
        for (int j = 0; j < 8; j++) tile[((t & 7) * 8 + j) * 264 + l] = v8[j];
    }
    __syncthreads();
    ushort* op = vtbuf + (size_t)bh * HDD * NL;
#pragma unroll
    for (int i = 0; i < 8; i++) {
        int d = i * 8 + (t >> 5);
        int p0 = (t & 31) * 8;              // output position, multiple of 8
        int kbase = (p0 & ~31) + ((p0 >> 3) & 3) * 4;  // m*32 + quad*4
        const ushort* tr = tile + d * 264 + kbase;
        uint4 o;
        o.x = (uint)tr[0]  | ((uint)tr[1]  << 16);
        o.y = (uint)tr[2]  | ((uint)tr[3]  << 16);
        o.z = (uint)tr[16] | ((uint)tr[17] << 16);
        o.w = (uint)tr[18] | ((uint)tr[19] << 16);
        *(uint4*)(op + (size_t)d * NL + p0) = o;
    }
}

// ---------------- K3: LN(img tokens) -> Q projection via MFMA (bf16 [B,S,E])
__global__ void __launch_bounds__(256) q_kernel(const float* __restrict__ img_x,
                                                const float* __restrict__ lw,
                                                const float* __restrict__ lb,
                                                const ushort* __restrict__ Wqt,
                                                const float* __restrict__ bq,
                                                bf16* __restrict__ qbuf) {
    int blk = blockIdx.x;
    int b = blk >> 7;
    int s0 = (blk & 127) << 5;
    int t = threadIdx.x;
    int sl = t & 31, ch = t >> 5;
    __shared__ float tile[NC * 33];
    __shared__ ushort At[32 * 264];
    __shared__ float part[256];
    __shared__ float mu_s[32], rs_s[32];
    const float* xp = img_x + ((size_t)b * NC) * NS + s0;
    for (int c0 = 0; c0 < 32; c0++) {
        int c = c0 * 8 + ch;
        tile[c * 33 + sl] = xp[(size_t)c * NS + sl];
    }
    __syncthreads();
    float ps = 0;
    for (int c = ch * 32; c < ch * 32 + 32; c++) ps += tile[c * 33 + sl];
    part[t] = ps;
    __syncthreads();
    if (t < 32) {
        float m = 0;
        for (int j = 0; j < 8; j++) m += part[j * 32 + t];
        mu_s[t] = m * (1.f / NC);
    }
    __syncthreads();
    float mu = mu_s[sl];
    ps = 0;
    for (int c = ch * 32; c < ch * 32 + 32; c++) {
        float d = tile[c * 33 + sl] - mu;
        ps += d * d;
    }
    part[t] = ps;
    __syncthreads();
    if (t < 32) {
        float vv = 0;
        for (int j = 0; j < 8; j++) vv += part[j * 32 + t];
        rs_s[t] = rsqrt_nr(vv * (1.f / NC) + 1e-5f);
    }
    __syncthreads();
    float rs = rs_s[sl];
    for (int c = ch * 32; c < ch * 32 + 32; c++) {
        At[sl * 264 + c] = us((tile[c * 33 + sl] - mu) * rs * lw[c] + lb[c]);
    }
    __syncthreads();

    int w = t >> 6, lane = t & 63, l16 = lane & 15, quad = lane >> 4;
    int r0 = (w & 1) * 16, e0 = (w >> 1) * 128;
    f32x4 zero = {0.f, 0.f, 0.f, 0.f};
    f32x4 acc[8];
#pragma unroll
    for (int dt = 0; dt < 8; dt++) acc[dt] = zero;
    const ushort* ap = At + (r0 + l16) * 264 + quad * 8;
    const ushort* bp = Wqt + (size_t)(e0 + l16) * NC + quad * 8;
#pragma unroll
    for (int kc = 0; kc < 8; kc++) {
        bf16x8 a = *(const bf16x8*)(ap + kc * 32);
#pragma unroll
        for (int dt = 0; dt < 8; dt++) {
            bf16x8 bb = *(const bf16x8*)(bp + (size_t)dt * 16 * NC + kc * 32);
            acc[dt] = __builtin_amdgcn_mfma_f32_16x16x32_bf16(a, bb, acc[dt], 0, 0, 0);
        }
    }
#pragma unroll
    for (int dt = 0; dt < 8; dt++) {
        int e = e0 + dt * 16 + l16;
        float bqv = bq[e];
#pragma unroll
        for (int r = 0; r < 4; r++) {
            int s = s0 + r0 + quad * 4 + r;
            qbuf[((size_t)b * NS + s) * NE + e] = __float2bfloat16(acc[dt][r] + bqv);
        }
    }
}

// ---------------- K4: barrier-free LDS-free MFMA attention.
// S^T = K.Q^T (lane col = query) -> lane-local softmax (+2 shfl_xor) ->
// P packed in registers IS the PV A-frag under the permuted-V key order.
__global__ void __launch_bounds__(256) attn_kernel(const bf16* __restrict__ qbuf,
                                                   const bf16* __restrict__ kbuf,
                                                   const ushort* __restrict__ vtbuf,
                                                   const int* __restrict__ masks,
                                                   bf16* __restrict__ obuf) {
    int blk = blockIdx.x;
    int st = blk & 63;
    int bh = blk >> 6;
    int h = bh & 3;
    int b = bh >> 2;
    int s0 = st << 6;
    int t = threadIdx.x;
    int w = t >> 6, lane = t & 63;
    int l16 = lane & 15, quad = lane >> 4;

    // Q B-frags: lane l16 = query row
    const ushort* qp = (const ushort*)qbuf +
                       ((size_t)(b * NS + s0 + w * 16 + l16)) * NE + h * HDD + quad * 8;
    bf16x8 qf0 = *(const bf16x8*)qp;
    bf16x8 qf1 = *(const bf16x8*)(qp + 32);

    f32x4 zero = {0.f, 0.f, 0.f, 0.f};
    f32x4 acc[16];
#pragma unroll
    for (int kt = 0; kt < 16; kt++) acc[kt] = zero;

    // QK^T transposed: A = K rows (lane l16 = key), B = Q rows -> D[key][query]
    const ushort* kp0 = (const ushort*)kbuf + ((size_t)(b * NL)) * NE + h * HDD + quad * 8;
#pragma unroll
    for (int kt = 0; kt < 16; kt++) {
        const ushort* kp = kp0 + (size_t)(kt * 16 + l16) * NE;
        bf16x8 af0 = *(const bf16x8*)kp;
        bf16x8 af1 = *(const bf16x8*)(kp + 32);
        acc[kt] = __builtin_amdgcn_mfma_f32_16x16x32_bf16(af0, qf0, acc[kt], 0, 0, 0);
        acc[kt] = __builtin_amdgcn_mfma_f32_16x16x32_bf16(af1, qf1, acc[kt], 0, 0, 0);
    }

    // lane (l16, quad) holds S^T rows key=kt*16+quad*4+r, col query=l16.
    // bf16-round, scale, mask; softmax is per-lane + 2 shuffles.
    const int* mp = masks + b * NL + quad * 4;
    float mx = -INFINITY;
#pragma unroll
    for (int kt = 0; kt < 16; kt++) {
        int4 mv = *(const int4*)(mp + kt * 16);
        float v0 = mv.x ? -INFINITY : bf16r(acc[kt][0]) * 0.125f;
        float v1 = mv.y ? -INFINITY : bf16r(acc[kt][1]) * 0.125f;
        float v2 = mv.z ? -INFINITY : bf16r(acc[kt][2]) * 0.125f;
        float v3 = mv.w ? -INFINITY : bf16r(acc[kt][3]) * 0.125f;
        acc[kt][0] = v0; acc[kt][1] = v1; acc[kt][2] = v2; acc[kt][3] = v3;
        mx = fmaxf(mx, fmaxf(fmaxf(v0, v1), fmaxf(v2, v3)));
    }
    mx = fmaxf(mx, __shfl_xor(mx, 16, 64));
    mx = fmaxf(mx, __shfl_xor(mx, 32, 64));
    float sm = 0.f;
#pragma unroll
    for (int kt = 0; kt < 16; kt++) {
#pragma unroll
        for (int r = 0; r < 4; r++) {
            float p = __expf(acc[kt][r] - mx);
            acc[kt][r] = p;
            sm += p;
        }
    }
    sm += __shfl_xor(sm, 16, 64);
    sm += __shfl_xor(sm, 32, 64);
    float inv = 1.f / sm;

    // pack P to bf16 pairs: pk[2kt] = keys (quad*4+0, +1), pk[2kt+1] = (+2, +3)
    uint pk[32];
#pragma unroll
    for (int kt = 0; kt < 16; kt++) {
        pk[2 * kt]     = pack2(acc[kt][0] * inv, acc[kt][1] * inv);
        pk[2 * kt + 1] = pack2(acc[kt][2] * inv, acc[kt][3] * inv);
    }

    // PV: A-frag for chunk m = (pk[4m], pk[4m+1], pk[4m+2], pk[4m+3]) by construction;
    // B-frag from permuted vtbuf rows (lane l16 = d index).
    f32x4 oacc[4];
#pragma unroll
    for (int dt = 0; dt < 4; dt++) oacc[dt] = zero;
    const ushort* vrow = vtbuf + (size_t)bh * HDD * NL + (size_t)l16 * NL + quad * 8;
#pragma unroll
    for (int m = 0; m < 8; m++) {
        U16 u = {pk[4 * m], pk[4 * m + 1], pk[4 * m + 2], pk[4 * m + 3]};
        bf16x8 pa = __builtin_bit_cast(bf16x8, u);
#pragma unroll
        for (int dt = 0; dt < 4; dt++) {
            bf16x8 vb = *(const bf16x8*)(vrow + (size_t)dt * 16 * NL + m * 32);
            oacc[dt] = __builtin_amdgcn_mfma_f32_16x16x32_bf16(pa, vb, oacc[dt], 0, 0, 0);
        }
    }
    // D rows = query (quad*4+r), cols = d (l16): same store pattern as round 3
    bf16* op = obuf + ((size_t)(b * NS + s0 + w * 16 + quad * 4)) * NE + h * HDD + l16;
#pragma unroll
    for (int dt = 0; dt < 4; dt++) {
#pragma unroll
        for (int r = 0; r < 4; r++)
            op[(size_t)r * NE + dt * 16] = __float2bfloat16(oacc[dt][r]);
    }
}

// ---------------- K5: Y^T = Wo^T . o^T via MFMA -> AdaLN -> +x -> out [B,C,S]
__global__ void __launch_bounds__(256) out_kernel(const bf16* __restrict__ obuf,
                                                  const ushort* __restrict__ Wot,
                                                  const float* __restrict__ bo,
                                                  const float* __restrict__ mod,
                                                  const float* __restrict__ img_x,
                                                  float* __restrict__ out) {
    int blk = blockIdx.x;
    int b = blk >> 6;
    int s0 = (blk & 63) << 6;
    int t = threadIdx.x;
    int w = t >> 6, lane = t & 63, l16 = lane & 15, quad = lane >> 4;
    int c0 = w * 64;

    f32x4 zero = {0.f, 0.f, 0.f, 0.f};
    f32x4 acc[4][4];
#pragma unroll
    for (int ct = 0; ct < 4; ct++)
#pragma unroll
        for (int st = 0; st < 4; st++) acc[ct][st] = zero;

    const ushort* ap0 = Wot + (size_t)(c0 + l16) * NE + quad * 8;
    const ushort* bp0 = (const ushort*)obuf + ((size_t)(b * NS + s0 + l16)) * NE + quad * 8;
#pragma unroll
    for (int kc = 0; kc < 8; kc++) {
        bf16x8 a[4], bb[4];
#pragma unroll
        for (int ct = 0; ct < 4; ct++)
            a[ct] = *(const bf16x8*)(ap0 + (size_t)ct * 16 * NE + kc * 32);
#pragma unroll
        for (int st = 0; st < 4; st++)
            bb[st] = *(const bf16x8*)(bp0 + (size_t)st * 16 * NE + kc * 32);
#pragma unroll
        for (int ct = 0; ct < 4; ct++)
#pragma unroll
            for (int st = 0; st < 4; st++)
                acc[ct][st] = __builtin_amdgcn_mfma_f32_16x16x32_bf16(a[ct], bb[st], acc[ct][st], 0, 0, 0);
    }

#pragma unroll
    for (int ct = 0; ct < 4; ct++) {
#pragma unroll
        for (int r = 0; r < 4; r++) {
            int c = c0 + ct * 16 + quad * 4 + r;
            float sh = mod[b * 768 + c];
            float scv = mod[b * 768 + 256 + c];
            float ga = mod[b * 768 + 512 + c];
            float bov = bo[c];
            const float* xr = img_x + ((size_t)(b * NC + c)) * NS + s0;
            float* orow = out + ((size_t)(b * NC + c)) * NS + s0;
#pragma unroll
            for (int st = 0; st < 4; st++) {
                float y = ga * ((acc[ct][st][r] + bov) * (1.f + scv) + sh) + xr[st * 16 + l16];
                orow[st * 16 + l16] = y;
            }
        }
    }
}

extern "C" void kernel_launch(void* const* d_in, const int* in_sizes, int n_in,
                              void* d_out, int out_size, void* d_ws, size_t ws_size,
                              hipStream_t stream) {
    const float* img_x = (const float*)d_in[0];
    const float* refs = (const float*)d_in[1];
    const int* masks = (const int*)d_in[2];
    const float* ref_embeds = (const float*)d_in[3];
    const float* ln_img_w = (const float*)d_in[4];
    const float* ln_img_b = (const float*)d_in[5];
    const float* ln_txt_w = (const float*)d_in[6];
    const float* ln_txt_b = (const float*)d_in[7];
    const float* Wq = (const float*)d_in[8];
    const float* bq = (const float*)d_in[9];
    const float* Wk = (const float*)d_in[10];
    const float* bk = (const float*)d_in[11];
    const float* Wv = (const float*)d_in[12];
    const float* bv = (const float*)d_in[13];
    const float* Wo = (const float*)d_in[14];
    const float* bo = (const float*)d_in[15];
    const float* W_ada = (const float*)d_in[16];
    const float* b_ada = (const float*)d_in[17];
    float* out = (float*)d_out;

    char* ws = (char*)d_ws;
    float* mod = (float*)ws;                               // 49152 B
    ushort* wqt = (ushort*)(ws + 49152);                   // 128 KB
    ushort* wkt = (ushort*)(ws + 180224);                  // 128 KB
    ushort* wvt = (ushort*)(ws + 311296);                  // 128 KB
    ushort* wot = (ushort*)(ws + 442368);                  // 128 KB
    bf16* kbuf = (bf16*)(ws + 573440);                     // 2 MB
    ushort* vtbuf = (ushort*)(ws + 2670592);               // 2 MB
    bf16* qbuf = (bf16*)(ws + 4767744);                    // 33.5 MB
    bf16* obuf = (bf16*)(ws + 38322176);                   // 33.5 MB
    bf16* vbuf = obuf;  // alias: dead after vt_kernel, before attn writes obuf

    hipLaunchKernelGGL(wt_kernel, dim3(32), dim3(256), 0, stream,
                       Wq, Wk, Wv, Wo, wqt, wkt, wvt, wot);
    hipLaunchKernelGGL(mod_kernel, dim3(NB), dim3(256), 0, stream,
                       ref_embeds, W_ada, b_ada, mod);
    hipLaunchKernelGGL(kv_kernel, dim3(NB * 4), dim3(256), 0, stream,
                       refs, ln_txt_w, ln_txt_b, wkt, bk, wvt, bv, kbuf, vbuf);
    hipLaunchKernelGGL(vt_kernel, dim3(NB * NHH), dim3(256), 0, stream,
                       vbuf, vtbuf);
    hipLaunchKernelGGL(q_kernel, dim3(NB * (NS / 32)), dim3(256), 0, stream,
                       img_x, ln_img_w, ln_img_b, wqt, bq, qbuf);
    hipLaunchKernelGGL(attn_kernel, dim3(NB * NHH * (NS / 64)), dim3(256), 0, stream,
                       qbuf, kbuf, vtbuf, masks, obuf);
    hipLaunchKernelGGL(out_kernel, dim3(NB * (NS / 64)), dim3(256), 0, stream,
                       obuf, wot, bo, mod, img_x, out);
}